// Round 4
// baseline (129.325 us; speedup 1.0000x reference)
//
#include <hip/hip_runtime.h>

#define N_NODES 200000
#define C 256
#define VC 16
#define VD 3
#define VDIM (VC * VD)   // 48
#define M_MOTIFS 50000
#define M_PAD 50048      // padded rows so GEMM grid divides evenly (50048 = 782*64)
#define CAP 64           // per-motif slot capacity; Poisson(4) => P(count>64) ~ 1e-36

#define NODE_BLOCKS ((N_NODES + 255) / 256)       // 782
#define CVT_BLOCKS  ((C * C) / (256 * 4))         // 64 (float4 per thread)
#define GATHER_BLOCKS (M_MOTIFS / 4)              // 12500 (4 waves/block, 1 motif/wave)
#define GEMM_BLOCKS (M_PAD / 64)                  // 782

typedef __attribute__((ext_vector_type(8))) __bf16 bf16x8;
typedef __attribute__((ext_vector_type(4))) float f32x4;

__device__ __forceinline__ unsigned short f2bf(float x) {
  unsigned u = __builtin_bit_cast(unsigned, x);
  u += 0x7fffu + ((u >> 16) & 1u);   // RNE
  return (unsigned short)(u >> 16);
}

// ---------------------------------------------------------------------------
// K1: slot-fill. rank = atomicAdd(cnt[m]); nodelist[m*64+rank] = i.
//     Extra blocks convert Ws->bf16.
// ---------------------------------------------------------------------------
__global__ __launch_bounds__(256) void fill_kernel(
    const int* __restrict__ seg, int* __restrict__ cnt,
    int* __restrict__ nodelist, const float* __restrict__ Ws,
    unsigned short* __restrict__ Wsb) {
  int b = blockIdx.x, t = threadIdx.x;
  if (b < NODE_BLOCKS) {
    int i = b * 256 + t;
    if (i < N_NODES) {
      int m = seg[i];
      int r = atomicAdd(&cnt[m], 1);
      if (r < CAP) nodelist[(size_t)m * CAP + r] = i;
    }
  } else {
    int i = ((b - NODE_BLOCKS) * 256 + t) * 4;
    float4 w = *(const float4*)(Ws + i);
    ushort4 o;
    o.x = f2bf(w.x); o.y = f2bf(w.y); o.z = f2bf(w.z); o.w = f2bf(w.w);
    *(ushort4*)(Wsb + i) = o;
  }
}

// ---------------------------------------------------------------------------
// K2: gather + mean + fused v 16x16 linear. ONE WAVE PER MOTIF (50K waves).
//     cnt and slot-id loads issued back-to-back before any branch (branch
//     needs only cnt -> waits vmcnt(1)). ONE clamped batch of 8 row loads
//     (dup index min(j,k-1): same-address L1 broadcast hit, no HBM cost),
//     single drain, predicated accumulate after all loads are in flight.
// ---------------------------------------------------------------------------
__global__ __launch_bounds__(256) void gather_kernel(
    const float* __restrict__ s, const float* __restrict__ v,
    const int* __restrict__ cnt, const int* __restrict__ nodelist,
    const float* __restrict__ Wv, const float* __restrict__ bv,
    unsigned short* __restrict__ s_motif, float* __restrict__ v_out) {
  int m = (blockIdx.x * 256 + threadIdx.x) >> 6;   // exact: 12500*4 = 50000
  int lane = threadIdx.x & 63;

  // both metadata loads in flight before any dependent work
  int k = cnt[m];                                       // wave-uniform
  int idv = nodelist[(size_t)m * CAP + (lane & 15)];    // 16 candidate ids

  if (k == 0) {                                    // ~1.8% of motifs
    ushort4 z; z.x = z.y = z.z = z.w = 0;
    ((ushort4*)(s_motif + (size_t)m * C))[lane] = z;
    if (lane < VDIM) v_out[(size_t)m * VDIM + lane] = bv[lane / 3];
    return;
  }

  int km1 = k - 1;
  int kc = min(k, CAP);

  // ---- single clamped batch: slots 0..7, all 8 rows in flight at once
  int i0 = __shfl(idv, 0, 64);
  int i1 = __shfl(idv, min(1, km1), 64);
  int i2 = __shfl(idv, min(2, km1), 64);
  int i3 = __shfl(idv, min(3, km1), 64);
  int i4 = __shfl(idv, min(4, km1), 64);
  int i5 = __shfl(idv, min(5, km1), 64);
  int i6 = __shfl(idv, min(6, km1), 64);
  int i7 = __shfl(idv, min(7, km1), 64);
  float4 a0 = ((const float4*)(s + (size_t)i0 * C))[lane];
  float4 a1 = ((const float4*)(s + (size_t)i1 * C))[lane];
  float4 a2 = ((const float4*)(s + (size_t)i2 * C))[lane];
  float4 a3 = ((const float4*)(s + (size_t)i3 * C))[lane];
  float4 a4 = ((const float4*)(s + (size_t)i4 * C))[lane];
  float4 a5 = ((const float4*)(s + (size_t)i5 * C))[lane];
  float4 a6 = ((const float4*)(s + (size_t)i6 * C))[lane];
  float4 a7 = ((const float4*)(s + (size_t)i7 * C))[lane];
  float vb0 = 0.f, vb1 = 0.f, vb2 = 0.f, vb3 = 0.f;
  float vb4 = 0.f, vb5 = 0.f, vb6 = 0.f, vb7 = 0.f;
  if (lane < VDIM) {
    vb0 = v[(size_t)i0 * VDIM + lane];
    vb1 = v[(size_t)i1 * VDIM + lane];
    vb2 = v[(size_t)i2 * VDIM + lane];
    vb3 = v[(size_t)i3 * VDIM + lane];
    vb4 = v[(size_t)i4 * VDIM + lane];
    vb5 = v[(size_t)i5 * VDIM + lane];
    vb6 = v[(size_t)i6 * VDIM + lane];
    vb7 = v[(size_t)i7 * VDIM + lane];
  }
  float4 acc = a0;
  float vacc = vb0;
  if (k > 1) { acc.x += a1.x; acc.y += a1.y; acc.z += a1.z; acc.w += a1.w; vacc += vb1; }
  if (k > 2) { acc.x += a2.x; acc.y += a2.y; acc.z += a2.z; acc.w += a2.w; vacc += vb2; }
  if (k > 3) { acc.x += a3.x; acc.y += a3.y; acc.z += a3.z; acc.w += a3.w; vacc += vb3; }
  if (k > 4) { acc.x += a4.x; acc.y += a4.y; acc.z += a4.z; acc.w += a4.w; vacc += vb4; }
  if (k > 5) { acc.x += a5.x; acc.y += a5.y; acc.z += a5.z; acc.w += a5.w; vacc += vb5; }
  if (k > 6) { acc.x += a6.x; acc.y += a6.y; acc.z += a6.z; acc.w += a6.w; vacc += vb6; }
  if (k > 7) { acc.x += a7.x; acc.y += a7.y; acc.z += a7.z; acc.w += a7.w; vacc += vb7; }

  // ---- rare tail: slots 8.. (2% of motifs)
  if (k > 8) {
    int idv2 = nodelist[(size_t)m * CAP + lane];
    for (int j = 8; j < kc; ++j) {
      int ij = __shfl(idv2, j, 64);
      float4 a = ((const float4*)(s + (size_t)ij * C))[lane];
      acc.x += a.x; acc.y += a.y; acc.z += a.z; acc.w += a.w;
      if (lane < VDIM) vacc += v[(size_t)ij * VDIM + lane];
    }
  }

  float rc = 1.0f / (float)k;
  ushort4 o;
  o.x = f2bf(acc.x * rc); o.y = f2bf(acc.y * rc);
  o.z = f2bf(acc.z * rc); o.w = f2bf(acc.w * rc);
  ((ushort4*)(s_motif + (size_t)m * C))[lane] = o;

  float vm = vacc * rc;   // lane c*3+d holds vmean[c][d]
  if (lane < VDIM) {
    int oo = lane / 3, d = lane - oo * 3;
    float vo = bv[oo];
#pragma unroll
    for (int c2 = 0; c2 < VC; ++c2)
      vo += Wv[oo * VC + c2] * __shfl(vm, c2 * 3 + d, 64);
    v_out[(size_t)m * VDIM + lane] = vo;
  }
}

// ---------------------------------------------------------------------------
// K3: direct-L2 bf16 MFMA GEMM. No LDS, no barriers. Block = 64 rows x 256
//     cols, 4 waves; wave w does cols [w*64, w*64+64), all 64 rows.
//     A (s_motif, just written, L2/L3-resident) and B (Wsb, 128 KB) fragments
//     loaded straight from global with the verified (row)*C + k0+kq bf16x8
//     pattern. A read once total (vs twice in the tiled version).
// ---------------------------------------------------------------------------
__global__ __launch_bounds__(256) void gemm_direct_kernel(
    const unsigned short* __restrict__ A16,   // s_motif bf16 [M_PAD][256]
    const unsigned short* __restrict__ B16,   // Ws bf16 [256][256]
    const float* __restrict__ bs, float* __restrict__ out) {
  int tid = threadIdx.x;
  int wave = tid >> 6, lane = tid & 63;
  int m0 = blockIdx.x * 64;
  int wn0 = wave * 64;
  int rl = lane & 15, kq = (lane >> 4) * 8;

  const unsigned short* Ab = A16 + (size_t)(m0 + rl) * C + kq;
  const unsigned short* Bb = B16 + (size_t)(wn0 + rl) * C + kq;

  f32x4 acc[4][4] = {};
#pragma unroll 2
  for (int k0 = 0; k0 < C; k0 += 32) {
    bf16x8 af[4], bfr[4];
#pragma unroll
    for (int i = 0; i < 4; ++i)
      af[i] = *(const bf16x8*)(Ab + (size_t)i * 16 * C + k0);
#pragma unroll
    for (int j = 0; j < 4; ++j)
      bfr[j] = *(const bf16x8*)(Bb + (size_t)j * 16 * C + k0);
#pragma unroll
    for (int i = 0; i < 4; ++i)
#pragma unroll
      for (int j = 0; j < 4; ++j)
        acc[i][j] = __builtin_amdgcn_mfma_f32_16x16x32_bf16(
            af[i], bfr[j], acc[i][j], 0, 0, 0);
  }

  int rq = (lane >> 4) * 4;
#pragma unroll
  for (int j = 0; j < 4; ++j) {
    int cn = wn0 + j * 16 + rl;
    float bias = bs[cn];
#pragma unroll
    for (int i = 0; i < 4; ++i) {
#pragma unroll
      for (int r = 0; r < 4; ++r) {
        int gm = m0 + i * 16 + rq + r;
        if (gm < M_MOTIFS) out[(size_t)gm * C + cn] = acc[i][j][r] + bias;
      }
    }
  }
}

extern "C" void kernel_launch(void* const* d_in, const int* in_sizes, int n_in,
                              void* d_out, int out_size, void* d_ws, size_t ws_size,
                              hipStream_t stream) {
  const float* s  = (const float*)d_in[0];
  const float* v  = (const float*)d_in[1];
  const int*   seg = (const int*)d_in[2];
  const float* Ws = (const float*)d_in[3];
  const float* bs = (const float*)d_in[4];
  const float* Wv = (const float*)d_in[5];
  const float* bv = (const float*)d_in[6];

  float* out   = (float*)d_out;
  float* s_out = out;
  float* v_out = out + (size_t)M_MOTIFS * C;

  // ws layout (~38.7 MB): [cnt M][nodelist M*CAP][Wsb C*C bf16][s_motif M_PAD*C bf16]
  int* cnt      = (int*)d_ws;
  int* nodelist = cnt + M_MOTIFS;
  unsigned short* Wsb     = (unsigned short*)(nodelist + (size_t)M_MOTIFS * CAP);
  unsigned short* s_motif = Wsb + (size_t)C * C;

  hipMemsetAsync(cnt, 0, M_MOTIFS * sizeof(int), stream);
  fill_kernel<<<NODE_BLOCKS + CVT_BLOCKS, 256, 0, stream>>>(seg, cnt, nodelist,
                                                            Ws, Wsb);
  gather_kernel<<<GATHER_BLOCKS, 256, 0, stream>>>(s, v, cnt, nodelist, Wv, bv,
                                                   s_motif, v_out);
  gemm_direct_kernel<<<GEMM_BLOCKS, 256, 0, stream>>>(s_motif, Wsb, bs, s_out);
}

// Round 5
// 127.689 us; speedup vs baseline: 1.0128x; 1.0128x over previous
//
#include <hip/hip_runtime.h>

#define N_NODES 200000
#define C 256
#define VC 16
#define VD 3
#define VDIM (VC * VD)   // 48
#define M_MOTIFS 50000
#define M_PAD 50048      // padded rows: 50048 = 782 * 64
#define CAP 64           // per-motif slot capacity; Poisson(4) => P(count>64) ~ 1e-36

#define NODE_BLOCKS ((N_NODES + 255) / 256)       // 782
#define CVT_BLOCKS  ((C * C) / (256 * 4))         // 64 (float4 per thread)
#define GATHER_BLOCKS (M_MOTIFS / 4)              // 12500 (4 waves/block, 1 motif/wave)
#define GEMM_BLOCKS 512                           // 2 per CU (64 KB LDS each)
#define NTILES (M_PAD / 64)                       // 782 row-tiles

typedef __attribute__((ext_vector_type(8))) __bf16 bf16x8;
typedef __attribute__((ext_vector_type(4))) float f32x4;

__device__ __forceinline__ unsigned short f2bf(float x) {
  unsigned u = __builtin_bit_cast(unsigned, x);
  u += 0x7fffu + ((u >> 16) & 1u);   // RNE
  return (unsigned short)(u >> 16);
}

// ---------------------------------------------------------------------------
// K1: slot-fill. rank = atomicAdd(cnt[m]); nodelist[m*64+rank] = i.
//     Extra blocks convert Ws->bf16.
// ---------------------------------------------------------------------------
__global__ __launch_bounds__(256) void fill_kernel(
    const int* __restrict__ seg, int* __restrict__ cnt,
    int* __restrict__ nodelist, const float* __restrict__ Ws,
    unsigned short* __restrict__ Wsb) {
  int b = blockIdx.x, t = threadIdx.x;
  if (b < NODE_BLOCKS) {
    int i = b * 256 + t;
    if (i < N_NODES) {
      int m = seg[i];
      int r = atomicAdd(&cnt[m], 1);
      if (r < CAP) nodelist[(size_t)m * CAP + r] = i;
    }
  } else {
    int i = ((b - NODE_BLOCKS) * 256 + t) * 4;
    float4 w = *(const float4*)(Ws + i);
    ushort4 o;
    o.x = f2bf(w.x); o.y = f2bf(w.y); o.z = f2bf(w.z); o.w = f2bf(w.w);
    *(ushort4*)(Wsb + i) = o;
  }
}

// ---------------------------------------------------------------------------
// K2: gather + mean + fused v 16x16 linear. ONE WAVE PER MOTIF (50K waves).
//     Round-3 structure; only change: idv load hoisted above the k==0 branch
//     so both metadata loads are in flight (branch waits vmcnt(1)).
// ---------------------------------------------------------------------------
__global__ __launch_bounds__(256) void gather_kernel(
    const float* __restrict__ s, const float* __restrict__ v,
    const int* __restrict__ cnt, const int* __restrict__ nodelist,
    const float* __restrict__ Wv, const float* __restrict__ bv,
    unsigned short* __restrict__ s_motif, float* __restrict__ v_out) {
  int m = (blockIdx.x * 256 + threadIdx.x) >> 6;   // exact: 12500*4 = 50000
  int lane = threadIdx.x & 63;

  int k = cnt[m];                                       // wave-uniform
  int idv = nodelist[(size_t)m * CAP + (lane & 15)];    // in flight w/ cnt

  if (k == 0) {                                    // ~1.8% of motifs
    ushort4 z; z.x = z.y = z.z = z.w = 0;
    ((ushort4*)(s_motif + (size_t)m * C))[lane] = z;
    if (lane < VDIM) v_out[(size_t)m * VDIM + lane] = bv[lane / 3];
    return;
  }

  int km1 = k - 1;
  int kc = min(k, CAP);

  // ---- batch 0: slots 0..3 (clamped; duplicates are same-address L1 hits)
  int i0 = __shfl(idv, 0, 64);
  int i1 = __shfl(idv, min(1, km1), 64);
  int i2 = __shfl(idv, min(2, km1), 64);
  int i3 = __shfl(idv, min(3, km1), 64);
  float4 a0 = ((const float4*)(s + (size_t)i0 * C))[lane];
  float4 a1 = ((const float4*)(s + (size_t)i1 * C))[lane];
  float4 a2 = ((const float4*)(s + (size_t)i2 * C))[lane];
  float4 a3 = ((const float4*)(s + (size_t)i3 * C))[lane];
  float vb0 = 0.f, vb1 = 0.f, vb2 = 0.f, vb3 = 0.f;
  if (lane < VDIM) {
    vb0 = v[(size_t)i0 * VDIM + lane];
    vb1 = v[(size_t)i1 * VDIM + lane];
    vb2 = v[(size_t)i2 * VDIM + lane];
    vb3 = v[(size_t)i3 * VDIM + lane];
  }
  float4 acc = a0;
  float vacc = vb0;
  if (k > 1) { acc.x += a1.x; acc.y += a1.y; acc.z += a1.z; acc.w += a1.w; vacc += vb1; }
  if (k > 2) { acc.x += a2.x; acc.y += a2.y; acc.z += a2.z; acc.w += a2.w; vacc += vb2; }
  if (k > 3) { acc.x += a3.x; acc.y += a3.y; acc.z += a3.z; acc.w += a3.w; vacc += vb3; }

  // ---- batch 1: slots 4..7 (37% of motifs)
  if (k > 4) {
    int i4 = __shfl(idv, min(4, km1), 64);
    int i5 = __shfl(idv, min(5, km1), 64);
    int i6 = __shfl(idv, min(6, km1), 64);
    int i7 = __shfl(idv, min(7, km1), 64);
    float4 b4 = ((const float4*)(s + (size_t)i4 * C))[lane];
    float4 b5 = ((const float4*)(s + (size_t)i5 * C))[lane];
    float4 b6 = ((const float4*)(s + (size_t)i6 * C))[lane];
    float4 b7 = ((const float4*)(s + (size_t)i7 * C))[lane];
    float w4 = 0.f, w5 = 0.f, w6 = 0.f, w7 = 0.f;
    if (lane < VDIM) {
      w4 = v[(size_t)i4 * VDIM + lane];
      w5 = v[(size_t)i5 * VDIM + lane];
      w6 = v[(size_t)i6 * VDIM + lane];
      w7 = v[(size_t)i7 * VDIM + lane];
    }
    acc.x += b4.x; acc.y += b4.y; acc.z += b4.z; acc.w += b4.w; vacc += w4;
    if (k > 5) { acc.x += b5.x; acc.y += b5.y; acc.z += b5.z; acc.w += b5.w; vacc += w5; }
    if (k > 6) { acc.x += b6.x; acc.y += b6.y; acc.z += b6.z; acc.w += b6.w; vacc += w6; }
    if (k > 7) { acc.x += b7.x; acc.y += b7.y; acc.z += b7.z; acc.w += b7.w; vacc += w7; }
  }

  // ---- rare tail: slots 8.. (2% of motifs)
  if (k > 8) {
    int idv2 = nodelist[(size_t)m * CAP + lane];
    for (int j = 8; j < kc; ++j) {
      int ij = __shfl(idv2, j, 64);
      float4 a = ((const float4*)(s + (size_t)ij * C))[lane];
      acc.x += a.x; acc.y += a.y; acc.z += a.z; acc.w += a.w;
      if (lane < VDIM) vacc += v[(size_t)ij * VDIM + lane];
    }
  }

  float rc = 1.0f / (float)k;
  ushort4 o;
  o.x = f2bf(acc.x * rc); o.y = f2bf(acc.y * rc);
  o.z = f2bf(acc.z * rc); o.w = f2bf(acc.w * rc);
  ((ushort4*)(s_motif + (size_t)m * C))[lane] = o;

  float vm = vacc * rc;   // lane c*3+d holds vmean[c][d]
  if (lane < VDIM) {
    int oo = lane / 3, d = lane - oo * 3;
    float vo = bv[oo];
#pragma unroll
    for (int c2 = 0; c2 < VC; ++c2)
      vo += Wv[oo * VC + c2] * __shfl(vm, c2 * 3 + d, 64);
    v_out[(size_t)m * VDIM + lane] = vo;
  }
}

// ---------------------------------------------------------------------------
// K3: persistent-B bf16 MFMA GEMM. 512 blocks (2/CU). Each block stages one
//     128-col half of Ws into 64 KB LDS ONCE (XOR-swizzled 16B chunks ->
//     conflict-free ds_read_b128), then grid-strides over 64-row tiles with
//     no further barriers. Per tile per wave: 8 A-loads (all in flight), then
//     8 k-steps x (8 LDS B-frags + 8 MFMAs). A read exactly once total.
// ---------------------------------------------------------------------------
__global__ __launch_bounds__(256, 2) void gemm_persistB_kernel(
    const unsigned short* __restrict__ A16,   // s_motif bf16 [M_PAD][256]
    const unsigned short* __restrict__ B16,   // Ws bf16 [256][256] (row=n)
    const float* __restrict__ bs, float* __restrict__ out) {
  __shared__ unsigned short Bs[128 * 256];    // 64 KB
  int tid = threadIdx.x;
  int half = blockIdx.x & 1;
  int bstart = blockIdx.x >> 1;               // 0..255
  int n0 = half * 128;

  // stage B-half: 4096 16B chunks, 16 per thread, swizzled byte ^ ((row&7)<<4)
#pragma unroll
  for (int it = 0; it < 16; ++it) {
    int chunk = it * 256 + tid;
    int row = chunk >> 5, cpos = chunk & 31;   // 32 chunks per 512B row
    bf16x8 w = *(const bf16x8*)(B16 + (size_t)(n0 + row) * C + cpos * 8);
    int byte = row * 512 + ((cpos * 16) ^ ((row & 7) << 4));
    *(bf16x8*)((char*)Bs + byte) = w;
  }
  __syncthreads();

  int wave = tid >> 6, lane = tid & 63;
  int rl = lane & 15;
  int quad = lane >> 4;
  int kq = quad * 8;        // k element offset of this lane's 16B chunk
  int rq = quad * 4;

  float bias[8];
#pragma unroll
  for (int j = 0; j < 8; ++j) bias[j] = bs[n0 + j * 16 + rl];

  for (int t = bstart; t < NTILES; t += 256) {
    int m0 = t * 64;
    int mrow = m0 + wave * 16 + rl;
    const unsigned short* Ab = A16 + (size_t)mrow * C + kq;
    bf16x8 af[8];
#pragma unroll
    for (int kk = 0; kk < 8; ++kk)          // 8 independent loads in flight
      af[kk] = *(const bf16x8*)(Ab + kk * 32);

    f32x4 acc[8] = {};
#pragma unroll
    for (int kk = 0; kk < 8; ++kk) {
#pragma unroll
      for (int j = 0; j < 8; ++j) {
        int rowl = j * 16 + rl;
        int byte = rowl * 512 + ((kk * 64 + quad * 16) ^ ((rowl & 7) << 4));
        bf16x8 bf = *(const bf16x8*)((const char*)Bs + byte);
        acc[j] = __builtin_amdgcn_mfma_f32_16x16x32_bf16(af[kk], bf, acc[j],
                                                         0, 0, 0);
      }
    }

#pragma unroll
    for (int j = 0; j < 8; ++j) {
      int cn = n0 + j * 16 + rl;
#pragma unroll
      for (int r = 0; r < 4; ++r) {
        int gm = m0 + wave * 16 + rq + r;
        if (gm < M_MOTIFS) out[(size_t)gm * C + cn] = acc[j][r] + bias[j];
      }
    }
  }
}

extern "C" void kernel_launch(void* const* d_in, const int* in_sizes, int n_in,
                              void* d_out, int out_size, void* d_ws, size_t ws_size,
                              hipStream_t stream) {
  const float* s  = (const float*)d_in[0];
  const float* v  = (const float*)d_in[1];
  const int*   seg = (const int*)d_in[2];
  const float* Ws = (const float*)d_in[3];
  const float* bs = (const float*)d_in[4];
  const float* Wv = (const float*)d_in[5];
  const float* bv = (const float*)d_in[6];

  float* out   = (float*)d_out;
  float* s_out = out;
  float* v_out = out + (size_t)M_MOTIFS * C;

  // ws layout (~38.7 MB): [cnt M][nodelist M*CAP][Wsb C*C bf16][s_motif M_PAD*C bf16]
  int* cnt      = (int*)d_ws;
  int* nodelist = cnt + M_MOTIFS;
  unsigned short* Wsb     = (unsigned short*)(nodelist + (size_t)M_MOTIFS * CAP);
  unsigned short* s_motif = Wsb + (size_t)C * C;

  hipMemsetAsync(cnt, 0, M_MOTIFS * sizeof(int), stream);
  fill_kernel<<<NODE_BLOCKS + CVT_BLOCKS, 256, 0, stream>>>(seg, cnt, nodelist,
                                                            Ws, Wsb);
  gather_kernel<<<GATHER_BLOCKS, 256, 0, stream>>>(s, v, cnt, nodelist, Wv, bv,
                                                   s_motif, v_out);
  gemm_persistB_kernel<<<GEMM_BLOCKS, 256, 0, stream>>>(s_motif, Wsb, bs, s_out);
}

// Round 6
// 108.142 us; speedup vs baseline: 1.1959x; 1.1807x over previous
//
#include <hip/hip_runtime.h>

#define N_NODES 200000
#define C 256
#define VC 16
#define VD 3
#define VDIM (VC * VD)   // 48
#define M_MOTIFS 50000
#define CAP 64           // per-motif slot capacity; Poisson(4) => P(count>64) ~ 1e-36

#define NODE_BLOCKS ((N_NODES + 255) / 256)       // 782
#define CVT_BLOCKS  ((C * C) / (256 * 4))         // 64 (float4 per thread)
#define GATHER_BLOCKS (M_MOTIFS / 4)              // 12500 (4 waves/block, 1 motif/wave)
#define GEMM_BLOCKS 512                           // 2 per CU (VGPR-limited)
#define NTILES (M_MOTIFS / 16)                    // 3125 row-tiles, exact

typedef __attribute__((ext_vector_type(8))) __bf16 bf16x8;
typedef __attribute__((ext_vector_type(4))) float f32x4;

__device__ __forceinline__ unsigned short f2bf(float x) {
  unsigned u = __builtin_bit_cast(unsigned, x);
  u += 0x7fffu + ((u >> 16) & 1u);   // RNE
  return (unsigned short)(u >> 16);
}

// ---------------------------------------------------------------------------
// K1: slot-fill. rank = atomicAdd(cnt[m]); nodelist[m*64+rank] = i.
//     Extra blocks convert Ws->bf16.
// ---------------------------------------------------------------------------
__global__ __launch_bounds__(256) void fill_kernel(
    const int* __restrict__ seg, int* __restrict__ cnt,
    int* __restrict__ nodelist, const float* __restrict__ Ws,
    unsigned short* __restrict__ Wsb) {
  int b = blockIdx.x, t = threadIdx.x;
  if (b < NODE_BLOCKS) {
    int i = b * 256 + t;
    if (i < N_NODES) {
      int m = seg[i];
      int r = atomicAdd(&cnt[m], 1);
      if (r < CAP) nodelist[(size_t)m * CAP + r] = i;
    }
  } else {
    int i = ((b - NODE_BLOCKS) * 256 + t) * 4;
    float4 w = *(const float4*)(Ws + i);
    ushort4 o;
    o.x = f2bf(w.x); o.y = f2bf(w.y); o.z = f2bf(w.z); o.w = f2bf(w.w);
    *(ushort4*)(Wsb + i) = o;
  }
}

// ---------------------------------------------------------------------------
// K2: gather + mean + fused v 16x16 linear. ONE WAVE PER MOTIF (50K waves).
//     EXACT round-3 structure (measured best: 104 us total).
// ---------------------------------------------------------------------------
__global__ __launch_bounds__(256) void gather_kernel(
    const float* __restrict__ s, const float* __restrict__ v,
    const int* __restrict__ cnt, const int* __restrict__ nodelist,
    const float* __restrict__ Wv, const float* __restrict__ bv,
    unsigned short* __restrict__ s_motif, float* __restrict__ v_out) {
  int m = (blockIdx.x * 256 + threadIdx.x) >> 6;   // exact: 12500*4 = 50000
  int lane = threadIdx.x & 63;
  int k = cnt[m];                                  // wave-uniform

  if (k == 0) {                                    // ~1.8% of motifs
    ushort4 z; z.x = z.y = z.z = z.w = 0;
    ((ushort4*)(s_motif + (size_t)m * C))[lane] = z;
    if (lane < VDIM) v_out[(size_t)m * VDIM + lane] = bv[lane / 3];
    return;
  }

  // independent of cnt: 16 candidate slot ids, one 64B coalesced read
  int idv = nodelist[(size_t)m * CAP + (lane & 15)];
  int km1 = k - 1;
  int kc = min(k, CAP);

  // ---- batch 0: slots 0..3 (clamped; duplicates are same-address L1 hits)
  int i0 = __shfl(idv, 0, 64);
  int i1 = __shfl(idv, min(1, km1), 64);
  int i2 = __shfl(idv, min(2, km1), 64);
  int i3 = __shfl(idv, min(3, km1), 64);
  float4 a0 = ((const float4*)(s + (size_t)i0 * C))[lane];
  float4 a1 = ((const float4*)(s + (size_t)i1 * C))[lane];
  float4 a2 = ((const float4*)(s + (size_t)i2 * C))[lane];
  float4 a3 = ((const float4*)(s + (size_t)i3 * C))[lane];
  float vb0 = 0.f, vb1 = 0.f, vb2 = 0.f, vb3 = 0.f;
  if (lane < VDIM) {
    vb0 = v[(size_t)i0 * VDIM + lane];
    vb1 = v[(size_t)i1 * VDIM + lane];
    vb2 = v[(size_t)i2 * VDIM + lane];
    vb3 = v[(size_t)i3 * VDIM + lane];
  }
  float4 acc = a0;
  float vacc = vb0;
  if (k > 1) { acc.x += a1.x; acc.y += a1.y; acc.z += a1.z; acc.w += a1.w; vacc += vb1; }
  if (k > 2) { acc.x += a2.x; acc.y += a2.y; acc.z += a2.z; acc.w += a2.w; vacc += vb2; }
  if (k > 3) { acc.x += a3.x; acc.y += a3.y; acc.z += a3.z; acc.w += a3.w; vacc += vb3; }

  // ---- batch 1: slots 4..7 (37% of motifs)
  if (k > 4) {
    int i4 = __shfl(idv, min(4, km1), 64);
    int i5 = __shfl(idv, min(5, km1), 64);
    int i6 = __shfl(idv, min(6, km1), 64);
    int i7 = __shfl(idv, min(7, km1), 64);
    float4 b4 = ((const float4*)(s + (size_t)i4 * C))[lane];
    float4 b5 = ((const float4*)(s + (size_t)i5 * C))[lane];
    float4 b6 = ((const float4*)(s + (size_t)i6 * C))[lane];
    float4 b7 = ((const float4*)(s + (size_t)i7 * C))[lane];
    float w4 = 0.f, w5 = 0.f, w6 = 0.f, w7 = 0.f;
    if (lane < VDIM) {
      w4 = v[(size_t)i4 * VDIM + lane];
      w5 = v[(size_t)i5 * VDIM + lane];
      w6 = v[(size_t)i6 * VDIM + lane];
      w7 = v[(size_t)i7 * VDIM + lane];
    }
    acc.x += b4.x; acc.y += b4.y; acc.z += b4.z; acc.w += b4.w; vacc += w4;
    if (k > 5) { acc.x += b5.x; acc.y += b5.y; acc.z += b5.z; acc.w += b5.w; vacc += w5; }
    if (k > 6) { acc.x += b6.x; acc.y += b6.y; acc.z += b6.z; acc.w += b6.w; vacc += w6; }
    if (k > 7) { acc.x += b7.x; acc.y += b7.y; acc.z += b7.z; acc.w += b7.w; vacc += w7; }
  }

  // ---- rare tail: slots 8.. (2% of motifs)
  if (k > 8) {
    int idv2 = nodelist[(size_t)m * CAP + lane];
    for (int j = 8; j < kc; ++j) {
      int ij = __shfl(idv2, j, 64);
      float4 a = ((const float4*)(s + (size_t)ij * C))[lane];
      acc.x += a.x; acc.y += a.y; acc.z += a.z; acc.w += a.w;
      if (lane < VDIM) vacc += v[(size_t)ij * VDIM + lane];
    }
  }

  float rc = 1.0f / (float)k;
  ushort4 o;
  o.x = f2bf(acc.x * rc); o.y = f2bf(acc.y * rc);
  o.z = f2bf(acc.z * rc); o.w = f2bf(acc.w * rc);
  ((ushort4*)(s_motif + (size_t)m * C))[lane] = o;

  float vm = vacc * rc;   // lane c*3+d holds vmean[c][d]
  if (lane < VDIM) {
    int oo = lane / 3, d = lane - oo * 3;
    float vo = bv[oo];
#pragma unroll
    for (int c2 = 0; c2 < VC; ++c2)
      vo += Wv[oo * VC + c2] * __shfl(vm, c2 * 3 + d, 64);
    v_out[(size_t)m * VDIM + lane] = vo;
  }
}

// ---------------------------------------------------------------------------
// K3: register-B bf16 MFMA GEMM. No LDS, no barriers, A read exactly once.
//     Each wave holds its full 64-col x 256-k B panel in 32 bf16x8 frags
//     (128 VGPR), loaded once from L2-resident Wsb. Grid-stride over 16-row
//     A tiles (50000 = 3125*16 exact, no guards). Per tile: 8 independent
//     A-loads + 32 MFMAs (4:1 MFMA:load, no LDS pipe).
// ---------------------------------------------------------------------------
__global__ __launch_bounds__(256, 2) void gemm_regB_kernel(
    const unsigned short* __restrict__ A16,   // s_motif bf16 [M][256]
    const unsigned short* __restrict__ B16,   // Ws bf16 [256][256] (row = n)
    const float* __restrict__ bs, float* __restrict__ out) {
  int tid = threadIdx.x;
  int wave = tid >> 6, lane = tid & 63;
  int wn0 = wave * 64;
  int rl = lane & 15;
  int quad = lane >> 4;
  int kq = quad * 8;          // k element offset of this lane's 16B chunk
  int rq = quad * 4;

  // ---- load full B panel for this wave's 64 cols: 32 frags, once ----
  const unsigned short* Bb = B16 + (size_t)(wn0 + rl) * C + kq;
  bf16x8 bf[8][4];
#pragma unroll
  for (int kk = 0; kk < 8; ++kk)
#pragma unroll
    for (int j = 0; j < 4; ++j)
      bf[kk][j] = *(const bf16x8*)(Bb + (size_t)j * 16 * C + kk * 32);

  float bias[4];
#pragma unroll
  for (int j = 0; j < 4; ++j) bias[j] = bs[wn0 + j * 16 + rl];

  for (int t = blockIdx.x; t < NTILES; t += GEMM_BLOCKS) {
    int m0 = t * 16;
    const unsigned short* Ab = A16 + (size_t)(m0 + rl) * C + kq;
    bf16x8 af[8];
#pragma unroll
    for (int kk = 0; kk < 8; ++kk)          // 8 independent loads in flight
      af[kk] = *(const bf16x8*)(Ab + kk * 32);

    f32x4 acc[4] = {};
#pragma unroll
    for (int kk = 0; kk < 8; ++kk)
#pragma unroll
      for (int j = 0; j < 4; ++j)
        acc[j] = __builtin_amdgcn_mfma_f32_16x16x32_bf16(af[kk], bf[kk][j],
                                                         acc[j], 0, 0, 0);

#pragma unroll
    for (int j = 0; j < 4; ++j) {
      int cn = wn0 + j * 16 + rl;
#pragma unroll
      for (int r = 0; r < 4; ++r)
        out[(size_t)(m0 + rq + r) * C + cn] = acc[j][r] + bias[j];
    }
  }
}

extern "C" void kernel_launch(void* const* d_in, const int* in_sizes, int n_in,
                              void* d_out, int out_size, void* d_ws, size_t ws_size,
                              hipStream_t stream) {
  const float* s  = (const float*)d_in[0];
  const float* v  = (const float*)d_in[1];
  const int*   seg = (const int*)d_in[2];
  const float* Ws = (const float*)d_in[3];
  const float* bs = (const float*)d_in[4];
  const float* Wv = (const float*)d_in[5];
  const float* bv = (const float*)d_in[6];

  float* out   = (float*)d_out;
  float* s_out = out;
  float* v_out = out + (size_t)M_MOTIFS * C;

  // ws layout (~38.3 MB): [cnt M][nodelist M*CAP][Wsb C*C bf16][s_motif M*C bf16]
  int* cnt      = (int*)d_ws;
  int* nodelist = cnt + M_MOTIFS;
  unsigned short* Wsb     = (unsigned short*)(nodelist + (size_t)M_MOTIFS * CAP);
  unsigned short* s_motif = Wsb + (size_t)C * C;
  // byte offsets: Wsb = 13,600,000 (16B-aligned); s_motif = 13,731,072 (16B-aligned)

  hipMemsetAsync(cnt, 0, M_MOTIFS * sizeof(int), stream);
  fill_kernel<<<NODE_BLOCKS + CVT_BLOCKS, 256, 0, stream>>>(seg, cnt, nodelist,
                                                            Ws, Wsb);
  gather_kernel<<<GATHER_BLOCKS, 256, 0, stream>>>(s, v, cnt, nodelist, Wv, bv,
                                                   s_motif, v_out);
  gemm_regB_kernel<<<GEMM_BLOCKS, 256, 0, stream>>>(s_motif, Wsb, bs, s_out);
}